// Round 1
// baseline (674.200 us; speedup 1.0000x reference)
//
#include <hip/hip_runtime.h>

#define NODES 50000
#define NEDGE 800000
#define HD 64
#define SLOPE 0.01f

// ---------------------------------------------------------------------------
// CSR build: count degrees, exclusive-scan to rowptr, fill column indices.
// ---------------------------------------------------------------------------

__global__ __launch_bounds__(256) void count_kernel(const int* __restrict__ ei,
                                                    int* __restrict__ deg, int E) {
    int e = blockIdx.x * blockDim.x + threadIdx.x;
    if (e < E) atomicAdd(&deg[ei[E + e]], 1);   // row 1 = dst
}

// Single-block 1024-thread exclusive scan over deg[0..n) -> rowptr[0..n],
// also emits inv_deg = 1/max(deg,1).
__global__ __launch_bounds__(1024) void scan_kernel(const int* __restrict__ deg,
                                                    int* __restrict__ rowptr,
                                                    float* __restrict__ inv_deg,
                                                    int n) {
    __shared__ int wsum[16];
    __shared__ int s_carry;
    const int tid = threadIdx.x;
    const int lane = tid & 63;
    const int wid = tid >> 6;
    if (tid == 0) s_carry = 0;
    __syncthreads();
    for (int base = 0; base < n; base += 1024) {
        int i = base + tid;
        int v = (i < n) ? deg[i] : 0;
        int x = v;
        #pragma unroll
        for (int d = 1; d < 64; d <<= 1) {
            int y = __shfl_up(x, d, 64);
            if (lane >= d) x += y;
        }
        if (lane == 63) wsum[wid] = x;
        __syncthreads();                    // (A) wave totals ready
        if (wid == 0) {
            int ws = (lane < 16) ? wsum[lane] : 0;
            int xs = ws;
            #pragma unroll
            for (int d = 1; d < 16; d <<= 1) {
                int y = __shfl_up(xs, d, 64);
                if (lane >= d) xs += y;
            }
            if (lane < 16) wsum[lane] = xs - ws;   // exclusive wave prefix
        }
        __syncthreads();                    // (B) exclusive prefixes ready
        int carry = s_carry;
        if (i < n) {
            rowptr[i] = carry + wsum[wid] + (x - v);
            inv_deg[i] = 1.0f / (float)((v > 1) ? v : 1);
        }
        __syncthreads();                    // (C) all readers done with s_carry
        if (tid == 1023) s_carry = carry + wsum[15] + x;  // block total
        __syncthreads();
    }
    if (tid == 0) rowptr[n] = s_carry;
}

__global__ __launch_bounds__(256) void fill_kernel(const int* __restrict__ ei,
                                                   const int* __restrict__ rowptr,
                                                   int* __restrict__ cursor,
                                                   int* __restrict__ colidx, int E) {
    int e = blockIdx.x * blockDim.x + threadIdx.x;
    if (e < E) {
        int src = ei[e];
        int dst = ei[E + e];
        int pos = atomicAdd(&cursor[dst], 1);
        colidx[rowptr[dst] + pos] = src;
    }
}

// ---------------------------------------------------------------------------
// Fused SAGE layer: wave-per-node mean-aggregate + (mean@Wl + b + self@Wr)
// + leaky_relu. Weight columns live in registers (lane j holds W[:, j]).
// ---------------------------------------------------------------------------

__global__ __launch_bounds__(256, 2) void sage_layer(
    const float* __restrict__ h_in,       // [N, 64]
    float* __restrict__ h_out,            // [N, 64]
    const int* __restrict__ rowptr,
    const int* __restrict__ colidx,
    const float* __restrict__ inv_deg,
    const float* __restrict__ Wl,         // [64, 64] row-major
    const float* __restrict__ bl,         // [64]
    const float* __restrict__ Wr,         // [64, 64]
    int n) {
    __shared__ float s_mean[4][HD];
    __shared__ float s_self[4][HD];
    const int lane = threadIdx.x & 63;
    const int wslot = threadIdx.x >> 6;

    // Stage weight columns into registers: wl[c] = Wl[c][lane].
    float wl[HD], wr[HD];
    #pragma unroll
    for (int c = 0; c < HD; ++c) {
        wl[c] = Wl[c * HD + lane];
        wr[c] = Wr[c * HD + lane];
    }
    const float bias = bl[lane];

    const int wave_id = blockIdx.x * 4 + wslot;
    const int nwaves = gridDim.x * 4;

    for (int node = wave_id; node < n; node += nwaves) {
        const int beg = rowptr[node];
        const int end = rowptr[node + 1];
        float sum = 0.0f;
        int k = beg;
        for (; k + 1 < end; k += 2) {
            int c0 = colidx[k];
            int c1 = colidx[k + 1];
            float a0 = h_in[c0 * HD + lane];
            float a1 = h_in[c1 * HD + lane];
            sum += a0;
            sum += a1;
        }
        if (k < end) sum += h_in[colidx[k] * HD + lane];

        const float mean = sum * inv_deg[node];
        const float self = h_in[node * HD + lane];

        s_mean[wslot][lane] = mean;
        s_self[wslot][lane] = self;
        __builtin_amdgcn_wave_barrier();   // wave-synchronous LDS: keep order

        float acc = bias;
        #pragma unroll
        for (int c4 = 0; c4 < HD / 4; ++c4) {
            // 4 consecutive same-type scalar LDS loads -> merged broadcast reads
            float m0 = s_mean[wslot][4 * c4 + 0];
            float m1 = s_mean[wslot][4 * c4 + 1];
            float m2 = s_mean[wslot][4 * c4 + 2];
            float m3 = s_mean[wslot][4 * c4 + 3];
            float f0 = s_self[wslot][4 * c4 + 0];
            float f1 = s_self[wslot][4 * c4 + 1];
            float f2 = s_self[wslot][4 * c4 + 2];
            float f3 = s_self[wslot][4 * c4 + 3];
            acc += m0 * wl[4 * c4 + 0] + m1 * wl[4 * c4 + 1]
                 + m2 * wl[4 * c4 + 2] + m3 * wl[4 * c4 + 3];
            acc += f0 * wr[4 * c4 + 0] + f1 * wr[4 * c4 + 1]
                 + f2 * wr[4 * c4 + 2] + f3 * wr[4 * c4 + 3];
        }
        __builtin_amdgcn_wave_barrier();   // don't sink reads past next write

        acc = (acc > 0.0f) ? acc : SLOPE * acc;
        h_out[node * HD + lane] = acc;
    }
}

// ---------------------------------------------------------------------------
// Output projection: out[node] = h[node,:] . Wout + bout  (wave-per-node).
// ---------------------------------------------------------------------------

__global__ __launch_bounds__(256) void out_kernel(const float* __restrict__ h,
                                                  const float* __restrict__ Wout,
                                                  const float* __restrict__ bout,
                                                  float* __restrict__ out, int n) {
    int gtid = blockIdx.x * blockDim.x + threadIdx.x;
    int node = gtid >> 6;
    int lane = gtid & 63;
    if (node >= n) return;
    float v = h[node * HD + lane] * Wout[lane];
    #pragma unroll
    for (int d = 32; d > 0; d >>= 1) v += __shfl_down(v, d, 64);
    if (lane == 0) out[node] = v + bout[0];
}

// ---------------------------------------------------------------------------

extern "C" void kernel_launch(void* const* d_in, const int* in_sizes, int n_in,
                              void* d_out, int out_size, void* d_ws, size_t ws_size,
                              hipStream_t stream) {
    const float* x   = (const float*)d_in[0];
    const int* ei    = (const int*)d_in[1];
    const float* Wl1 = (const float*)d_in[2];
    const float* bl1 = (const float*)d_in[3];
    const float* Wr1 = (const float*)d_in[4];
    const float* Wl2 = (const float*)d_in[5];
    const float* bl2 = (const float*)d_in[6];
    const float* Wr2 = (const float*)d_in[7];
    const float* Wl3 = (const float*)d_in[8];
    const float* bl3 = (const float*)d_in[9];
    const float* Wr3 = (const float*)d_in[10];
    const float* Wout = (const float*)d_in[11];
    const float* bout = (const float*)d_in[12];
    float* out = (float*)d_out;

    const int N = in_sizes[0] / HD;       // 50000
    const int E = in_sizes[1] / 2;        // 800000

    // Workspace layout (all 4-byte elements)
    int* deg      = (int*)d_ws;                     // [N]
    int* cursor   = deg + N;                        // [N]
    int* rowptr   = cursor + N;                     // [N+1]
    float* invdeg = (float*)(rowptr + N + 1);       // [N]
    int* colidx   = (int*)(invdeg + N);             // [E]
    float* hA     = (float*)(colidx + E);           // [N*64]
    float* hB     = hA + (size_t)N * HD;            // [N*64]

    // Zero deg + cursor (contiguous)
    hipMemsetAsync(deg, 0, (size_t)2 * N * sizeof(int), stream);

    const int eb = (E + 255) / 256;
    count_kernel<<<eb, 256, 0, stream>>>(ei, deg, E);
    scan_kernel<<<1, 1024, 0, stream>>>(deg, rowptr, invdeg, N);
    fill_kernel<<<eb, 256, 0, stream>>>(ei, rowptr, cursor, colidx, E);

    const int lgrid = 1024;
    sage_layer<<<lgrid, 256, 0, stream>>>(x,  hA, rowptr, colidx, invdeg, Wl1, bl1, Wr1, N);
    sage_layer<<<lgrid, 256, 0, stream>>>(hA, hB, rowptr, colidx, invdeg, Wl2, bl2, Wr2, N);
    sage_layer<<<lgrid, 256, 0, stream>>>(hB, hA, rowptr, colidx, invdeg, Wl3, bl3, Wr3, N);

    const int ob = (N * HD + 255) / 256;
    out_kernel<<<ob, 256, 0, stream>>>(hA, Wout, bout, out, N);
}